// Round 1
// baseline (1186.463 us; speedup 1.0000x reference)
//
#include <hip/hip_runtime.h>
#include <hip/hip_bf16.h>
#include <stdint.h>

// QuantizedLinear: y = x @ (Wq * scale[:,None])^T + bias
// M=8192 (B*S), K=4096, N=11008. f32 in, f32 out, int8 weights (wire: int32 or int8, auto-detected).
// Strategy: convert x and Wq to bf16 in d_ws (W is exact in bf16), run m97-structure
// bf16 MFMA GEMM (128x128 tile, BK=32, global_load_lds width=16), epilogue applies scale+bias.

#define M_TOTAL 8192
#define K_TOTAL 4096
#define N_TOTAL 11008

#define BM 128
#define BN 128
#define BK 32

typedef __attribute__((ext_vector_type(8))) short short8_t;  // 8 bf16 (4 VGPRs)
typedef __attribute__((ext_vector_type(4))) float f32x4;     // 4 fp32 acc

__device__ inline ushort f2bf(float f) {
    __hip_bfloat16 h = __float2bfloat16(f);
    union { __hip_bfloat16 h; ushort u; } cv;
    cv.h = h;
    return cv.u;
}

// ---------------- conversion passes ----------------

__global__ __launch_bounds__(256) void cvt_x_kernel(const float* __restrict__ in,
                                                    ushort* __restrict__ out, int nquads) {
    int stride = gridDim.x * blockDim.x;
    for (int i = blockIdx.x * blockDim.x + threadIdx.x; i < nquads; i += stride) {
        float4 v = reinterpret_cast<const float4*>(in)[i];
        ushort4 o;
        o.x = f2bf(v.x); o.y = f2bf(v.y); o.z = f2bf(v.z); o.w = f2bf(v.w);
        reinterpret_cast<ushort4*>(out)[i] = o;
    }
}

// Weights arrive either as int32 (one int8 value per 4B word) or packed int8.
// Detect: scan first 256 words; any |v|>127 => packed int8. Uniform across all blocks.
__global__ __launch_bounds__(256) void cvt_w_kernel(const int* __restrict__ in,
                                                    ushort* __restrict__ out, int nquads) {
    bool is8 = false;
    for (int i = 0; i < 256; ++i) {
        int v = in[i];
        if (v < -127 || v > 127) { is8 = true; break; }
    }
    int stride = gridDim.x * blockDim.x;
    if (!is8) {
        for (int i = blockIdx.x * blockDim.x + threadIdx.x; i < nquads; i += stride) {
            int4 v = reinterpret_cast<const int4*>(in)[i];
            ushort4 o;
            o.x = f2bf((float)v.x); o.y = f2bf((float)v.y);
            o.z = f2bf((float)v.z); o.w = f2bf((float)v.w);
            reinterpret_cast<ushort4*>(out)[i] = o;
        }
    } else {
        for (int i = blockIdx.x * blockDim.x + threadIdx.x; i < nquads; i += stride) {
            int packed = in[i];  // 4 int8 values
            ushort4 o;
            o.x = f2bf((float)(int)(signed char)(packed & 0xff));
            o.y = f2bf((float)(int)(signed char)((packed >> 8) & 0xff));
            o.z = f2bf((float)(int)(signed char)((packed >> 16) & 0xff));
            o.w = f2bf((float)(int)(signed char)((packed >> 24) & 0xff));
            reinterpret_cast<ushort4*>(out)[i] = o;
        }
    }
}

// ---------------- main GEMM (m97 structure) ----------------
// A = x_bf16 [M][K] row-major; B = w_bf16 [N][K] row-major ("B^T input").
// 256 threads = 4 waves in 2x2; each wave computes 64x64 = 4x4 fragments of 16x16.

#define GLOAD16(g, l) __builtin_amdgcn_global_load_lds( \
    (const __attribute__((address_space(1))) void*)(g), \
    (__attribute__((address_space(3))) void*)(l), 16, 0, 0)

__global__ __launch_bounds__(256) void gemm_kernel(const ushort* __restrict__ A,
                                                   const ushort* __restrict__ B,
                                                   const float* __restrict__ scale,
                                                   const float* __restrict__ bias,
                                                   float* __restrict__ C) {
    __shared__ ushort As[BM * BK];  // [128][32] bf16, linear (row stride 64B)
    __shared__ ushort Bs[BN * BK];

    const int tid  = threadIdx.x;
    const int wv   = tid >> 6;
    const int lane = tid & 63;

    const int nbn = N_TOTAL / BN;  // 86
    const int bm  = blockIdx.x / nbn;
    const int bn  = blockIdx.x % nbn;

    const int wm = wv >> 1;  // 0..1
    const int wn = wv & 1;   // 0..1

    // staging: per round r in {0,1}: rows [r*64 + wv*16, +16), lane covers row wv*16+lane/4, 8 bf16 at k=8*(lane&3)
    const int srow  = wv * 16 + (lane >> 2);
    const int selem = (lane & 3) * 8;

    const ushort* a_src0 = A + (size_t)(bm * BM + srow) * K_TOTAL + selem;
    const ushort* a_src1 = a_src0 + (size_t)64 * K_TOTAL;
    const ushort* b_src0 = B + (size_t)(bn * BN + srow) * K_TOTAL + selem;
    const ushort* b_src1 = b_src0 + (size_t)64 * K_TOTAL;

    // wave-uniform LDS bases (global_load_lds writes lds_base + lane*16)
    ushort* as_dst0 = &As[(size_t)(wv * 16) * BK];
    ushort* as_dst1 = &As[(size_t)(64 + wv * 16) * BK];
    ushort* bs_dst0 = &Bs[(size_t)(wv * 16) * BK];
    ushort* bs_dst1 = &Bs[(size_t)(64 + wv * 16) * BK];

    const int fr = lane & 15;  // A: m-within-16; B: n-within-16; C: col
    const int fq = lane >> 4;  // k-block 0..3; C: row-quad

    f32x4 acc[4][4] = {};

#pragma unroll 1
    for (int kt = 0; kt < K_TOTAL / BK; ++kt) {
        GLOAD16(a_src0, as_dst0);
        GLOAD16(a_src1, as_dst1);
        GLOAD16(b_src0, bs_dst0);
        GLOAD16(b_src1, bs_dst1);
        a_src0 += BK; a_src1 += BK; b_src0 += BK; b_src1 += BK;
        __syncthreads();

        short8_t af[4], bf[4];
#pragma unroll
        for (int fm = 0; fm < 4; ++fm)
            af[fm] = *reinterpret_cast<const short8_t*>(&As[(wm * 64 + fm * 16 + fr) * BK + fq * 8]);
#pragma unroll
        for (int fn = 0; fn < 4; ++fn)
            bf[fn] = *reinterpret_cast<const short8_t*>(&Bs[(wn * 64 + fn * 16 + fr) * BK + fq * 8]);
#pragma unroll
        for (int fm = 0; fm < 4; ++fm)
#pragma unroll
            for (int fn = 0; fn < 4; ++fn)
                acc[fm][fn] = __builtin_amdgcn_mfma_f32_16x16x32_bf16(af[fm], bf[fn], acc[fm][fn], 0, 0, 0);
        __syncthreads();
    }

    // epilogue: C[row][col] = acc * scale[col] + bias[col]
    const int crow0 = bm * BM + wm * 64;
    const int ccol0 = bn * BN + wn * 64;
#pragma unroll
    for (int fn = 0; fn < 4; ++fn) {
        const int col = ccol0 + fn * 16 + fr;
        const float s = scale[col];
        const float b = bias[col];
#pragma unroll
        for (int fm = 0; fm < 4; ++fm) {
            const int row = crow0 + fm * 16 + fq * 4;
            float* cp = C + (size_t)row * N_TOTAL + col;
#pragma unroll
            for (int r = 0; r < 4; ++r)
                cp[(size_t)r * N_TOTAL] = acc[fm][fn][r] * s + b;
        }
    }
}

// ---------------- fallback (only if ws_size too small): tiled f32 vector GEMM ----------------

__global__ __launch_bounds__(256) void gemm_fallback(const float* __restrict__ x,
                                                     const int* __restrict__ w,
                                                     const float* __restrict__ scale,
                                                     const float* __restrict__ bias,
                                                     float* __restrict__ C) {
    bool is8 = false;
    for (int i = 0; i < 256; ++i) {
        int v = w[i];
        if (v < -127 || v > 127) { is8 = true; break; }
    }
    const signed char* w8 = (const signed char*)w;

    __shared__ float As[64][16];
    __shared__ float Bs[64][16];
    const int nbn = N_TOTAL / 64;  // 172
    const int bm = blockIdx.x / nbn;
    const int bn = blockIdx.x % nbn;
    const int tid = threadIdx.x;
    const int tx = tid & 15, ty = tid >> 4;

    float acc[4][4] = {};
    for (int kt = 0; kt < K_TOTAL; kt += 16) {
        for (int i = 0; i < 4; ++i) {
            int idx = tid + i * 256;  // 0..1023
            int r = idx >> 4, c = idx & 15;
            As[r][c] = x[(size_t)(bm * 64 + r) * K_TOTAL + kt + c];
            size_t widx = (size_t)(bn * 64 + r) * K_TOTAL + kt + c;
            Bs[r][c] = is8 ? (float)w8[widx] : (float)w[widx];
        }
        __syncthreads();
        for (int kk = 0; kk < 16; ++kk) {
            float a[4], b[4];
            for (int i = 0; i < 4; ++i) a[i] = As[ty * 4 + i][kk];
            for (int j = 0; j < 4; ++j) b[j] = Bs[tx * 4 + j][kk];
            for (int i = 0; i < 4; ++i)
                for (int j = 0; j < 4; ++j) acc[i][j] += a[i] * b[j];
        }
        __syncthreads();
    }
    for (int j = 0; j < 4; ++j) {
        int col = bn * 64 + tx * 4 + j;
        float s = scale[col], bb = bias[col];
        for (int i = 0; i < 4; ++i) {
            int row = bm * 64 + ty * 4 + i;
            C[(size_t)row * N_TOTAL + col] = acc[i][j] * s + bb;
        }
    }
}

// ---------------- launch ----------------

extern "C" void kernel_launch(void* const* d_in, const int* in_sizes, int n_in,
                              void* d_out, int out_size, void* d_ws, size_t ws_size,
                              hipStream_t stream) {
    const float* x     = (const float*)d_in[0];
    const int*   wq    = (const int*)d_in[1];
    const float* scale = (const float*)d_in[2];
    const float* bias  = (const float*)d_in[3];
    float*       out   = (float*)d_out;

    const size_t x_elems = (size_t)M_TOTAL * K_TOTAL;  // 33,554,432
    const size_t w_elems = (size_t)N_TOTAL * K_TOTAL;  // 45,088,768
    const size_t need = (x_elems + w_elems) * sizeof(ushort);  // 150 MiB

    if (ws_size >= need) {
        ushort* xb = (ushort*)d_ws;
        ushort* wb = (ushort*)((char*)d_ws + x_elems * sizeof(ushort));
        cvt_x_kernel<<<2048, 256, 0, stream>>>(x, xb, (int)(x_elems / 4));
        cvt_w_kernel<<<2048, 256, 0, stream>>>(wq, wb, (int)(w_elems / 4));
        dim3 grid((M_TOTAL / BM) * (N_TOTAL / BN));  // 64*86 = 5504
        gemm_kernel<<<grid, 256, 0, stream>>>(xb, wb, scale, bias, out);
    } else {
        dim3 grid((M_TOTAL / 64) * (N_TOTAL / 64));  // 128*172
        gemm_fallback<<<grid, 256, 0, stream>>>(x, wq, scale, bias, out);
    }
}

// Round 2
// 807.088 us; speedup vs baseline: 1.4701x; 1.4701x over previous
//
#include <hip/hip_runtime.h>
#include <hip/hip_bf16.h>
#include <stdint.h>

// QuantizedLinear: y = x @ (Wq * scale[:,None])^T + bias
// M=8192, K=4096, N=11008. Round 2: 256x256 8-phase schedule (T1+T2+T3+T4+T5):
//   - BM=BN=256, BK=64, 512 thr = 8 waves (2M x 4N), per-wave 128x64 output
//   - LDS 128 KiB: 2 dbuf x {A[2 halves][128x64], B[2 halves][128x64]} bf16
//   - st-swizzle: LDS slot (row, c16) holds global col16 c16 ^ (row&7); applied via
//     inverse-swizzled GLOBAL source addr (gload_lds dest stays linear) + swizzled ds_read
//   - per phase: ds_read subtile + 1 half-tile prefetch (2 gload_lds) -> s_barrier ->
//     lgkmcnt(0) -> setprio(1) 16 MFMA setprio(0) -> [P3: counted vmcnt] -> s_barrier
//   - vmcnt(4) once per K-tile (2 half-tiles in flight), never 0 in main loop
//   - bijective XCD swizzle (1376 blocks = 8 x 172)

#define M_TOTAL 8192
#define K_TOTAL 4096
#define N_TOTAL 11008
#define NT (K_TOTAL / 64)      // 64 K-tiles of BK=64
#define HK ((size_t)128 * K_TOTAL)  // element offset of half-tile row 128

typedef __attribute__((ext_vector_type(8))) short short8_t;  // 8 bf16
typedef __attribute__((ext_vector_type(4))) float f32x4;

__device__ inline ushort f2bf(float f) {
    union { __hip_bfloat16 h; ushort u; } cv;
    cv.h = __float2bfloat16(f);
    return cv.u;
}

// ---------------- conversion passes (unchanged from round 1) ----------------

__global__ __launch_bounds__(256) void cvt_x_kernel(const float* __restrict__ in,
                                                    ushort* __restrict__ out, int nquads) {
    int stride = gridDim.x * blockDim.x;
    for (int i = blockIdx.x * blockDim.x + threadIdx.x; i < nquads; i += stride) {
        float4 v = reinterpret_cast<const float4*>(in)[i];
        ushort4 o;
        o.x = f2bf(v.x); o.y = f2bf(v.y); o.z = f2bf(v.z); o.w = f2bf(v.w);
        reinterpret_cast<ushort4*>(out)[i] = o;
    }
}

__global__ __launch_bounds__(256) void cvt_w_kernel(const int* __restrict__ in,
                                                    ushort* __restrict__ out, int nquads) {
    bool is8 = false;
    for (int i = 0; i < 256; ++i) {
        int v = in[i];
        if (v < -127 || v > 127) { is8 = true; break; }
    }
    int stride = gridDim.x * blockDim.x;
    if (!is8) {
        for (int i = blockIdx.x * blockDim.x + threadIdx.x; i < nquads; i += stride) {
            int4 v = reinterpret_cast<const int4*>(in)[i];
            ushort4 o;
            o.x = f2bf((float)v.x); o.y = f2bf((float)v.y);
            o.z = f2bf((float)v.z); o.w = f2bf((float)v.w);
            reinterpret_cast<ushort4*>(out)[i] = o;
        }
    } else {
        for (int i = blockIdx.x * blockDim.x + threadIdx.x; i < nquads; i += stride) {
            int packed = in[i];
            ushort4 o;
            o.x = f2bf((float)(int)(signed char)(packed & 0xff));
            o.y = f2bf((float)(int)(signed char)((packed >> 8) & 0xff));
            o.z = f2bf((float)(int)(signed char)((packed >> 16) & 0xff));
            o.w = f2bf((float)(int)(signed char)((packed >> 24) & 0xff));
            reinterpret_cast<ushort4*>(out)[i] = o;
        }
    }
}

// ---------------- 256x256 8-phase GEMM ----------------

#define GLOAD16(g, l) __builtin_amdgcn_global_load_lds( \
    (const __attribute__((address_space(1))) void*)(g), \
    (__attribute__((address_space(3))) void*)(l), 16, 0, 0)

// LDS map (ushort units): buf*32768 + {A: half*8192 | B: 16384 + half*8192}
// half-tile = 128 rows x 64 bf16 (128 B/row), chunk = 8 rows = 1024 B, 16 chunks/half.

#define PHASE(MH, KK, STAGEBLK, TAILBLK) {                                        \
    short8_t af[4];                                                               \
    _Pragma("unroll")                                                             \
    for (int i = 0; i < 4; ++i)                                                   \
        af[i] = *(const short8_t*)(rdA + ((MH)*4 + i)*1024 + fr64 +               \
                                   ((KK) ? kcol1 : kcol0));                       \
    if ((MH) == 0) {                                                              \
        bf[KK][0] = *(const short8_t*)(rdB + bb0 + ((KK) ? kcol1 : kcol0));       \
        bf[KK][1] = *(const short8_t*)(rdB + bb1 + ((KK) ? kcol1 : kcol0));       \
        bf[KK][2] = *(const short8_t*)(rdB + bb2 + ((KK) ? kcol1 : kcol0));       \
        bf[KK][3] = *(const short8_t*)(rdB + bb3 + ((KK) ? kcol1 : kcol0));       \
    }                                                                             \
    STAGEBLK                                                                      \
    __builtin_amdgcn_s_barrier();                                                 \
    asm volatile("s_waitcnt lgkmcnt(0)" ::: "memory");                            \
    __builtin_amdgcn_s_setprio(1);                                                \
    _Pragma("unroll")                                                             \
    for (int i = 0; i < 4; ++i) {                                                 \
        _Pragma("unroll")                                                         \
        for (int n = 0; n < 4; ++n)                                               \
            acc[(MH)*4 + i][n] = __builtin_amdgcn_mfma_f32_16x16x32_bf16(         \
                af[i], bf[KK][n], acc[(MH)*4 + i][n], 0, 0, 0);                   \
    }                                                                             \
    __builtin_amdgcn_s_setprio(0);                                                \
    TAILBLK                                                                       \
    __builtin_amdgcn_s_barrier();                                                 \
}

__global__ __launch_bounds__(512, 2) void gemm_kernel(const ushort* __restrict__ A,
                                                      const ushort* __restrict__ B,
                                                      const float* __restrict__ scale,
                                                      const float* __restrict__ bias,
                                                      float* __restrict__ C) {
    __shared__ ushort sh[65536];  // 128 KiB

    const int tid  = threadIdx.x;
    const int wv   = tid >> 6;      // 0..7
    const int lane = tid & 63;
    const int wm   = wv >> 2;       // 0..1 (M half)
    const int wn   = wv & 3;        // 0..3 (N quarter)

    // bijective XCD swizzle: nwg = 1376 = 8 * 172
    const int nbn = N_TOTAL / 256;  // 43
    const int swzid = (blockIdx.x & 7) * ((M_TOTAL / 256) * nbn / 8) + (blockIdx.x >> 3);
    const int bm = swzid / nbn;
    const int bn = swzid % nbn;

    // fragment-read geometry
    const int fr   = lane & 15;
    const int fq   = lane >> 4;
    const int swz  = fr & 7;
    const int fr64 = fr * 64;
    const int kcol0 = ((0 + fq) ^ swz) * 8;   // K-half 0: col16 = fq
    const int kcol1 = ((4 + fq) ^ swz) * 8;   // K-half 1: col16 = 4+fq
    const int nr0 = wn * 64;
    const int bb0 = ((nr0 +  0) >> 7) * 8192 + (((nr0 +  0) & 127) + fr) * 64;
    const int bb1 = ((nr0 + 16) >> 7) * 8192 + (((nr0 + 16) & 127) + fr) * 64;
    const int bb2 = ((nr0 + 32) >> 7) * 8192 + (((nr0 + 32) & 127) + fr) * 64;
    const int bb3 = ((nr0 + 48) >> 7) * 8192 + (((nr0 + 48) & 127) + fr) * 64;

    // staging geometry: chunk = 8 rows; wave stages chunks c0,c1; source col16 inverse-swizzled
    const int c0 = wv * 2, c1 = wv * 2 + 1;
    const int rl = lane >> 3;
    const int scol = (lane & 7) ^ rl;
    const size_t off0 = (size_t)(c0 * 8 + rl) * K_TOTAL + scol * 8;
    const size_t off1 = (size_t)(c1 * 8 + rl) * K_TOTAL + scol * 8;

    const ushort* aS = A + (size_t)bm * 256 * K_TOTAL;
    const ushort* bS = B + (size_t)bn * 256 * K_TOTAL;

    f32x4 acc[8][4] = {};

    // ---- prologue: stage A(0), B(0) -> buf0; B(1) -> buf1 (12 loads) ----
    GLOAD16(aS + off0,            sh + c0 * 512);
    GLOAD16(aS + off1,            sh + c1 * 512);
    GLOAD16(aS + HK + off0,       sh + 8192 + c0 * 512);
    GLOAD16(aS + HK + off1,       sh + 8192 + c1 * 512);
    GLOAD16(bS + off0,            sh + 16384 + c0 * 512);
    GLOAD16(bS + off1,            sh + 16384 + c1 * 512);
    GLOAD16(bS + HK + off0,       sh + 24576 + c0 * 512);
    GLOAD16(bS + HK + off1,       sh + 24576 + c1 * 512);
    GLOAD16(bS + 64 + off0,       sh + 32768 + 16384 + c0 * 512);
    GLOAD16(bS + 64 + off1,       sh + 32768 + 16384 + c1 * 512);
    GLOAD16(bS + 64 + HK + off0,  sh + 32768 + 24576 + c0 * 512);
    GLOAD16(bS + 64 + HK + off1,  sh + 32768 + 24576 + c1 * 512);
    asm volatile("s_waitcnt vmcnt(4)" ::: "memory");  // tile0 landed; B(1) in flight
    __builtin_amdgcn_s_barrier();

    // ---- main loop: tile t computes from buf (t&1); stages A(t+1) @P0/P1, B(t+2) @P2/P3 ----
#pragma unroll 1
    for (int t = 0; t < NT; ++t) {
        const int bsel = t & 1;
        const ushort* rdA = sh + (bsel << 15) + (wm << 13);
        const ushort* rdB = sh + (bsel << 15) + 16384;
        ushort* stA = sh + ((bsel ^ 1) << 15);          // A halves of tile t+1
        ushort* stB = sh + (bsel << 15) + 16384;        // B halves of tile t+2 (same parity)
        const ushort* aSrc = aS + (size_t)(t + 1) * 64;
        const ushort* bSrc = bS + (size_t)(t + 2) * 64;
        const bool doA = (t + 1 < NT);
        const bool doB = (t + 2 < NT);

        short8_t bf[2][4];

        PHASE(0, 0,
            { if (doA) { GLOAD16(aSrc + off0, stA + c0 * 512);
                         GLOAD16(aSrc + off1, stA + c1 * 512); } },
            {})
        PHASE(0, 1,
            { if (doA) { GLOAD16(aSrc + HK + off0, stA + 8192 + c0 * 512);
                         GLOAD16(aSrc + HK + off1, stA + 8192 + c1 * 512); } },
            {})
        PHASE(1, 0,
            { if (doB) { GLOAD16(bSrc + off0, stB + c0 * 512);
                         GLOAD16(bSrc + off1, stB + c1 * 512); } },
            {})
        PHASE(1, 1,
            { if (doB) { GLOAD16(bSrc + HK + off0, stB + 8192 + c0 * 512);
                         GLOAD16(bSrc + HK + off1, stB + 8192 + c1 * 512); } },
            { if (doA) {
                  if (doB) { asm volatile("s_waitcnt vmcnt(4)" ::: "memory"); }
                  else     { asm volatile("s_waitcnt vmcnt(0)" ::: "memory"); }
              } })
    }

    // ---- epilogue: C[row][col] = acc * scale[col] + bias[col] ----
    const int crow0 = bm * 256 + wm * 128;
    const int ccol0 = bn * 256 + wn * 64;
#pragma unroll
    for (int fn = 0; fn < 4; ++fn) {
        const int col = ccol0 + fn * 16 + fr;
        const float s = scale[col];
        const float b = bias[col];
#pragma unroll
        for (int fm = 0; fm < 8; ++fm) {
            const int row = crow0 + fm * 16 + fq * 4;
            float* cp = C + (size_t)row * N_TOTAL + col;
#pragma unroll
            for (int j = 0; j < 4; ++j)
                cp[(size_t)j * N_TOTAL] = acc[fm][fn][j] * s + b;
        }
    }
}

// ---------------- fallback (ws too small): tiled f32 vector GEMM ----------------

__global__ __launch_bounds__(256) void gemm_fallback(const float* __restrict__ x,
                                                     const int* __restrict__ w,
                                                     const float* __restrict__ scale,
                                                     const float* __restrict__ bias,
                                                     float* __restrict__ C) {
    bool is8 = false;
    for (int i = 0; i < 256; ++i) {
        int v = w[i];
        if (v < -127 || v > 127) { is8 = true; break; }
    }
    const signed char* w8 = (const signed char*)w;

    __shared__ float As[64][16];
    __shared__ float Bs[64][16];
    const int nbn = N_TOTAL / 64;
    const int bm = blockIdx.x / nbn;
    const int bn = blockIdx.x % nbn;
    const int tid = threadIdx.x;
    const int tx = tid & 15, ty = tid >> 4;

    float acc[4][4] = {};
    for (int kt = 0; kt < K_TOTAL; kt += 16) {
        for (int i = 0; i < 4; ++i) {
            int idx = tid + i * 256;
            int r = idx >> 4, c = idx & 15;
            As[r][c] = x[(size_t)(bm * 64 + r) * K_TOTAL + kt + c];
            size_t widx = (size_t)(bn * 64 + r) * K_TOTAL + kt + c;
            Bs[r][c] = is8 ? (float)w8[widx] : (float)w[widx];
        }
        __syncthreads();
        for (int kk = 0; kk < 16; ++kk) {
            float a[4], b[4];
            for (int i = 0; i < 4; ++i) a[i] = As[ty * 4 + i][kk];
            for (int j = 0; j < 4; ++j) b[j] = Bs[tx * 4 + j][kk];
            for (int i = 0; i < 4; ++i)
                for (int j = 0; j < 4; ++j) acc[i][j] += a[i] * b[j];
        }
        __syncthreads();
    }
    for (int j = 0; j < 4; ++j) {
        int col = bn * 64 + tx * 4 + j;
        float s = scale[col], bb = bias[col];
        for (int i = 0; i < 4; ++i) {
            int row = bm * 64 + ty * 4 + i;
            C[(size_t)row * N_TOTAL + col] = acc[i][j] * s + bb;
        }
    }
}

// ---------------- launch ----------------

extern "C" void kernel_launch(void* const* d_in, const int* in_sizes, int n_in,
                              void* d_out, int out_size, void* d_ws, size_t ws_size,
                              hipStream_t stream) {
    const float* x     = (const float*)d_in[0];
    const int*   wq    = (const int*)d_in[1];
    const float* scale = (const float*)d_in[2];
    const float* bias  = (const float*)d_in[3];
    float*       out   = (float*)d_out;

    const size_t x_elems = (size_t)M_TOTAL * K_TOTAL;
    const size_t w_elems = (size_t)N_TOTAL * K_TOTAL;
    const size_t need = (x_elems + w_elems) * sizeof(ushort);

    if (ws_size >= need) {
        ushort* xb = (ushort*)d_ws;
        ushort* wb = (ushort*)((char*)d_ws + x_elems * sizeof(ushort));
        cvt_x_kernel<<<2048, 256, 0, stream>>>(x, xb, (int)(x_elems / 4));
        cvt_w_kernel<<<2048, 256, 0, stream>>>(wq, wb, (int)(w_elems / 4));
        dim3 grid((M_TOTAL / 256) * (N_TOTAL / 256));  // 32*43 = 1376
        gemm_kernel<<<grid, 512, 0, stream>>>(xb, wb, scale, bias, out);
    } else {
        dim3 grid((M_TOTAL / 64) * (N_TOTAL / 64));
        gemm_fallback<<<grid, 256, 0, stream>>>(x, wq, scale, bias, out);
    }
}

// Round 3
// 475.850 us; speedup vs baseline: 2.4934x; 1.6961x over previous
//
#include <hip/hip_runtime.h>
#include <hip/hip_bf16.h>
#include <stdint.h>

// QuantizedLinear: y = x @ (Wq * scale[:,None])^T + bias
// Round 3: int8 MFMA path. W is int8 EXACT; x quantized per-row to int8
// (s_x = rowmax/127). GEMM in i32 (mfma_i32_16x16x64_i8, 2x OPS/instr vs bf16),
// epilogue y = acc * s_x[row]*scale[col] + bias[col].
// Same verified 256x256 8-phase schedule as round 2, BK=128 *bytes* per row
// (i8), so the swizzle/staging geometry is byte-identical to round 2's bf16.

#define M_TOTAL 8192
#define K_TOTAL 4096
#define N_TOTAL 11008
#define NT 32                       // K-tiles of BK=128 i8
#define HKB ((size_t)128 * K_TOTAL) // byte offset of half-tile row 128 (K bytes = 4096)

typedef __attribute__((ext_vector_type(4))) int int4v;   // 4 VGPR: i8 MFMA A/B/C

__device__ inline ushort f2bf(float f) {
    union { __hip_bfloat16 h; ushort u; } cv;
    cv.h = __float2bfloat16(f);
    return cv.u;
}

// ---------------- x quantization: per-row absmax -> int8 ----------------
// one block per row (256 thr, 4 waves); each thread handles 16 f32.

__global__ __launch_bounds__(256) void quant_x_kernel(const float* __restrict__ x,
                                                      signed char* __restrict__ xq,
                                                      float* __restrict__ sx) {
    const int row = blockIdx.x;
    const int tid = threadIdx.x;
    const float* xr = x + (size_t)row * K_TOTAL + tid * 16;

    float4 v0 = reinterpret_cast<const float4*>(xr)[0];
    float4 v1 = reinterpret_cast<const float4*>(xr)[1];
    float4 v2 = reinterpret_cast<const float4*>(xr)[2];
    float4 v3 = reinterpret_cast<const float4*>(xr)[3];

    float m = 0.f;
    m = fmaxf(m, fmaxf(fmaxf(fabsf(v0.x), fabsf(v0.y)), fmaxf(fabsf(v0.z), fabsf(v0.w))));
    m = fmaxf(m, fmaxf(fmaxf(fabsf(v1.x), fabsf(v1.y)), fmaxf(fabsf(v1.z), fabsf(v1.w))));
    m = fmaxf(m, fmaxf(fmaxf(fabsf(v2.x), fabsf(v2.y)), fmaxf(fabsf(v2.z), fabsf(v2.w))));
    m = fmaxf(m, fmaxf(fmaxf(fabsf(v3.x), fabsf(v3.y)), fmaxf(fabsf(v3.z), fabsf(v3.w))));

    for (int d = 1; d < 64; d <<= 1) m = fmaxf(m, __shfl_xor(m, d));
    __shared__ float wm[4];
    if ((tid & 63) == 0) wm[tid >> 6] = m;
    __syncthreads();
    m = fmaxf(fmaxf(wm[0], wm[1]), fmaxf(wm[2], wm[3]));

    const float inv = (m > 0.f) ? (127.f / m) : 0.f;
    if (tid == 0) sx[row] = (m > 0.f) ? (m / 127.f) : 0.f;

    int q[16];
    const float* vv = &v0.x;
    float tmp[16] = {v0.x,v0.y,v0.z,v0.w, v1.x,v1.y,v1.z,v1.w,
                     v2.x,v2.y,v2.z,v2.w, v3.x,v3.y,v3.z,v3.w};
    (void)vv;
#pragma unroll
    for (int i = 0; i < 16; ++i) {
        int t = __float2int_rn(tmp[i] * inv);
        q[i] = t > 127 ? 127 : (t < -127 ? -127 : t);
    }
    int4v o;
#pragma unroll
    for (int w = 0; w < 4; ++w)
        o[w] = (q[w*4] & 255) | ((q[w*4+1] & 255) << 8) |
               ((q[w*4+2] & 255) << 16) | ((q[w*4+3] & 255) << 24);
    *reinterpret_cast<int4v*>(xq + (size_t)row * K_TOTAL + tid * 16) = o;
}

// ---------------- W unpack: int32 wire (or packed int8) -> int8 ----------------

__global__ __launch_bounds__(256) void cvt_w_kernel(const int* __restrict__ in,
                                                    signed char* __restrict__ out, int nitems) {
    bool is8 = false;
    for (int i = 0; i < 256; ++i) {
        int v = in[i];
        if (v < -127 || v > 127) { is8 = true; break; }
    }
    int stride = gridDim.x * blockDim.x;
    if (!is8) {
        for (int i = blockIdx.x * blockDim.x + threadIdx.x; i < nitems; i += stride) {
            const int* p = in + (size_t)i * 16;
            int4v o;
#pragma unroll
            for (int w = 0; w < 4; ++w)
                o[w] = (p[w*4] & 255) | ((p[w*4+1] & 255) << 8) |
                       ((p[w*4+2] & 255) << 16) | ((p[w*4+3] & 255) << 24);
            *reinterpret_cast<int4v*>(out + (size_t)i * 16) = o;
        }
    } else {
        const int4v* in16 = reinterpret_cast<const int4v*>(in);
        for (int i = blockIdx.x * blockDim.x + threadIdx.x; i < nitems; i += stride)
            *reinterpret_cast<int4v*>(out + (size_t)i * 16) = in16[i];
    }
}

// ---------------- 256x256 8-phase i8 GEMM ----------------

#define GLOAD16(g, l) __builtin_amdgcn_global_load_lds( \
    (const __attribute__((address_space(1))) void*)(g), \
    (__attribute__((address_space(3))) void*)(l), 16, 0, 0)

// LDS map (bytes): buf*65536 + {A: half*16384 | B: 32768 + half*16384}
// half-tile = 128 rows x 128 B; chunk = 8 rows = 1024 B; 16 chunks/half.
// Swizzle: 16B granule g stored at g ^ (row&7); applied inverse on global src.

#define PHASE(MH, KK, STAGEBLK, TAILBLK) {                                        \
    int4v af[4];                                                                  \
    _Pragma("unroll")                                                             \
    for (int i = 0; i < 4; ++i)                                                   \
        af[i] = *(const int4v*)(rdA + ((MH)*64 + i*16 + fr)*128 +                 \
                                ((KK) ? kx1 : kx0));                              \
    if ((MH) == 0) {                                                              \
        bf[KK][0] = *(const int4v*)(rdB + bb0 + ((KK) ? kx1 : kx0));              \
        bf[KK][1] = *(const int4v*)(rdB + bb1 + ((KK) ? kx1 : kx0));              \
        bf[KK][2] = *(const int4v*)(rdB + bb2 + ((KK) ? kx1 : kx0));              \
        bf[KK][3] = *(const int4v*)(rdB + bb3 + ((KK) ? kx1 : kx0));              \
    }                                                                             \
    STAGEBLK                                                                      \
    __builtin_amdgcn_s_barrier();                                                 \
    asm volatile("s_waitcnt lgkmcnt(0)" ::: "memory");                            \
    __builtin_amdgcn_s_setprio(1);                                                \
    _Pragma("unroll")                                                             \
    for (int i = 0; i < 4; ++i) {                                                 \
        _Pragma("unroll")                                                         \
        for (int n = 0; n < 4; ++n)                                               \
            acc[(MH)*4 + i][n] = __builtin_amdgcn_mfma_i32_16x16x64_i8(           \
                af[i], bf[KK][n], acc[(MH)*4 + i][n], 0, 0, 0);                   \
    }                                                                             \
    __builtin_amdgcn_s_setprio(0);                                                \
    TAILBLK                                                                       \
    __builtin_amdgcn_s_barrier();                                                 \
}

__global__ __launch_bounds__(512, 2) void gemm_kernel(const unsigned char* __restrict__ A,
                                                      const unsigned char* __restrict__ B,
                                                      const float* __restrict__ sx,
                                                      const float* __restrict__ scale,
                                                      const float* __restrict__ bias,
                                                      float* __restrict__ C) {
    __shared__ unsigned char sh[131072];  // 128 KiB

    const int tid  = threadIdx.x;
    const int wv   = tid >> 6;      // 0..7
    const int lane = tid & 63;
    const int wm   = wv >> 2;       // 0..1 (M half)
    const int wn   = wv & 3;        // 0..3 (N quarter)

    // bijective XCD swizzle: nwg = 1376 = 8 * 172
    const int nbn = N_TOTAL / 256;  // 43
    const int swzid = (blockIdx.x & 7) * ((M_TOTAL / 256) * nbn / 8) + (blockIdx.x >> 3);
    const int bm = swzid / nbn;
    const int bn = swzid % nbn;

    // fragment-read geometry (byte offsets)
    const int fr  = lane & 15;      // row-in-16 / C col
    const int fq  = lane >> 4;      // k-granule group 0..3 / C row-quad
    const int swz = fr & 7;
    const int kx0 = ((0 + fq) ^ swz) * 16;   // K-half 0: granules 0..3
    const int kx1 = ((4 + fq) ^ swz) * 16;   // K-half 1: granules 4..7
    const int bb0 = 32768 + (wn >> 1) * 16384 + (((wn & 1) * 64 +  0 + fr)) * 128;
    const int bb1 = 32768 + (wn >> 1) * 16384 + (((wn & 1) * 64 + 16 + fr)) * 128;
    const int bb2 = 32768 + (wn >> 1) * 16384 + (((wn & 1) * 64 + 32 + fr)) * 128;
    const int bb3 = 32768 + (wn >> 1) * 16384 + (((wn & 1) * 64 + 48 + fr)) * 128;

    // staging: chunk = 8 rows x 128 B; wave stages chunks c0,c1; src granule inverse-swizzled
    const int c0 = wv * 2, c1 = wv * 2 + 1;
    const int rl = lane >> 3;                 // row within chunk 0..7
    const int sg = (lane & 7) ^ rl;           // source granule
    const size_t off0 = (size_t)(c0 * 8 + rl) * K_TOTAL + sg * 16;
    const size_t off1 = (size_t)(c1 * 8 + rl) * K_TOTAL + sg * 16;

    const unsigned char* aS = A + (size_t)bm * 256 * K_TOTAL;
    const unsigned char* bS = B + (size_t)bn * 256 * K_TOTAL;

    int4v acc[8][4] = {};

    // ---- prologue: stage A(0),B(0) -> buf0; B(1) -> buf1 ----
    GLOAD16(aS + off0,             sh + c0 * 1024);
    GLOAD16(aS + off1,             sh + c1 * 1024);
    GLOAD16(aS + HKB + off0,       sh + 16384 + c0 * 1024);
    GLOAD16(aS + HKB + off1,       sh + 16384 + c1 * 1024);
    GLOAD16(bS + off0,             sh + 32768 + c0 * 1024);
    GLOAD16(bS + off1,             sh + 32768 + c1 * 1024);
    GLOAD16(bS + HKB + off0,       sh + 49152 + c0 * 1024);
    GLOAD16(bS + HKB + off1,       sh + 49152 + c1 * 1024);
    GLOAD16(bS + 128 + off0,       sh + 65536 + 32768 + c0 * 1024);
    GLOAD16(bS + 128 + off1,       sh + 65536 + 32768 + c1 * 1024);
    GLOAD16(bS + 128 + HKB + off0, sh + 65536 + 49152 + c0 * 1024);
    GLOAD16(bS + 128 + HKB + off1, sh + 65536 + 49152 + c1 * 1024);
    asm volatile("s_waitcnt vmcnt(4)" ::: "memory");  // tile0 landed; B(1) in flight
    __builtin_amdgcn_s_barrier();

    // ---- main loop: tile t from buf (t&1); stage A(t+1) @P0/P1, B(t+2) @P2/P3 ----
#pragma unroll 1
    for (int t = 0; t < NT; ++t) {
        const int bsel = t & 1;
        const unsigned char* rdA = sh + (bsel << 16) + (wm << 14);
        const unsigned char* rdB = sh + (bsel << 16);   // bb* include +32768
        unsigned char* stA = sh + ((bsel ^ 1) << 16);
        unsigned char* stB = sh + (bsel << 16) + 32768;
        const unsigned char* aSrc = aS + (size_t)(t + 1) * 128;
        const unsigned char* bSrc = bS + (size_t)(t + 2) * 128;
        const bool doA = (t + 1 < NT);
        const bool doB = (t + 2 < NT);

        int4v bf[2][4];

        PHASE(0, 0,
            { if (doA) { GLOAD16(aSrc + off0, stA + c0 * 1024);
                         GLOAD16(aSrc + off1, stA + c1 * 1024); } },
            {})
        PHASE(0, 1,
            { if (doA) { GLOAD16(aSrc + HKB + off0, stA + 16384 + c0 * 1024);
                         GLOAD16(aSrc + HKB + off1, stA + 16384 + c1 * 1024); } },
            {})
        PHASE(1, 0,
            { if (doB) { GLOAD16(bSrc + off0, stB + c0 * 1024);
                         GLOAD16(bSrc + off1, stB + c1 * 1024); } },
            {})
        PHASE(1, 1,
            { if (doB) { GLOAD16(bSrc + HKB + off0, stB + 16384 + c0 * 1024);
                         GLOAD16(bSrc + HKB + off1, stB + 16384 + c1 * 1024); } },
            { if (doA) {
                  if (doB) { asm volatile("s_waitcnt vmcnt(4)" ::: "memory"); }
                  else     { asm volatile("s_waitcnt vmcnt(0)" ::: "memory"); }
              } })
    }

    // ---- epilogue: y = acc * sx[row]*scale[col] + bias[col] ----
    const int crow0 = bm * 256 + wm * 128;
    const int ccol0 = bn * 256 + wn * 64;
    float scv[4], bsv[4];
#pragma unroll
    for (int n = 0; n < 4; ++n) {
        const int col = ccol0 + n * 16 + fr;
        scv[n] = scale[col];
        bsv[n] = bias[col];
    }
#pragma unroll
    for (int fm = 0; fm < 8; ++fm) {
#pragma unroll
        for (int j = 0; j < 4; ++j) {
            const int row = crow0 + fm * 16 + fq * 4 + j;
            const float sr = sx[row];
            float* cp = C + (size_t)row * N_TOTAL + ccol0 + fr;
#pragma unroll
            for (int n = 0; n < 4; ++n)
                cp[n * 16] = (float)acc[fm][n][j] * (sr * scv[n]) + bsv[n];
        }
    }
}

// ---------------- fallback (ws too small): tiled f32 vector GEMM ----------------

__global__ __launch_bounds__(256) void gemm_fallback(const float* __restrict__ x,
                                                     const int* __restrict__ w,
                                                     const float* __restrict__ scale,
                                                     const float* __restrict__ bias,
                                                     float* __restrict__ C) {
    bool is8 = false;
    for (int i = 0; i < 256; ++i) {
        int v = w[i];
        if (v < -127 || v > 127) { is8 = true; break; }
    }
    const signed char* w8 = (const signed char*)w;

    __shared__ float As[64][16];
    __shared__ float Bs[64][16];
    const int nbn = N_TOTAL / 64;
    const int bm = blockIdx.x / nbn;
    const int bn = blockIdx.x % nbn;
    const int tid = threadIdx.x;
    const int tx = tid & 15, ty = tid >> 4;

    float acc[4][4] = {};
    for (int kt = 0; kt < K_TOTAL; kt += 16) {
        for (int i = 0; i < 4; ++i) {
            int idx = tid + i * 256;
            int r = idx >> 4, c = idx & 15;
            As[r][c] = x[(size_t)(bm * 64 + r) * K_TOTAL + kt + c];
            size_t widx = (size_t)(bn * 64 + r) * K_TOTAL + kt + c;
            Bs[r][c] = is8 ? (float)w8[widx] : (float)w[widx];
        }
        __syncthreads();
        for (int kk = 0; kk < 16; ++kk) {
            float a[4], b[4];
            for (int i = 0; i < 4; ++i) a[i] = As[ty * 4 + i][kk];
            for (int j = 0; j < 4; ++j) b[j] = Bs[tx * 4 + j][kk];
            for (int i = 0; i < 4; ++i)
                for (int j = 0; j < 4; ++j) acc[i][j] += a[i] * b[j];
        }
        __syncthreads();
    }
    for (int j = 0; j < 4; ++j) {
        int col = bn * 64 + tx * 4 + j;
        float s = scale[col], bb = bias[col];
        for (int i = 0; i < 4; ++i) {
            int row = bm * 64 + ty * 4 + i;
            C[(size_t)row * N_TOTAL + col] = acc[i][j] * s + bb;
        }
    }
}

// ---------------- launch ----------------

extern "C" void kernel_launch(void* const* d_in, const int* in_sizes, int n_in,
                              void* d_out, int out_size, void* d_ws, size_t ws_size,
                              hipStream_t stream) {
    const float* x     = (const float*)d_in[0];
    const int*   wq    = (const int*)d_in[1];
    const float* scale = (const float*)d_in[2];
    const float* bias  = (const float*)d_in[3];
    float*       out   = (float*)d_out;

    const size_t x_bytes = (size_t)M_TOTAL * K_TOTAL;          // 33,554,432 (i8)
    const size_t w_bytes = (size_t)N_TOTAL * K_TOTAL;          // 45,088,768 (i8)
    const size_t need = x_bytes + w_bytes + M_TOTAL * sizeof(float);

    if (ws_size >= need) {
        signed char* xq = (signed char*)d_ws;
        signed char* wb = (signed char*)d_ws + x_bytes;
        float*       sx = (float*)((char*)d_ws + x_bytes + w_bytes);

        quant_x_kernel<<<M_TOTAL, 256, 0, stream>>>(x, xq, sx);
        cvt_w_kernel<<<2048, 256, 0, stream>>>(wq, wb, (int)(w_bytes / 16));
        dim3 grid((M_TOTAL / 256) * (N_TOTAL / 256));  // 32*43 = 1376
        gemm_kernel<<<grid, 512, 0, stream>>>((const unsigned char*)xq,
                                              (const unsigned char*)wb,
                                              sx, scale, bias, out);
    } else {
        dim3 grid((M_TOTAL / 64) * (N_TOTAL / 64));
        gemm_fallback<<<grid, 256, 0, stream>>>(x, wq, scale, bias, out);
    }
}

// Round 4
// 463.204 us; speedup vs baseline: 2.5614x; 1.0273x over previous
//
#include <hip/hip_runtime.h>
#include <hip/hip_bf16.h>
#include <stdint.h>

// QuantizedLinear: y = x @ (Wq * scale[:,None])^T + bias
// Round 4: i8 MFMA, 128x128 tile, BK=128, 4 waves, 64 KiB LDS -> 2 blocks/CU.
// Rationale: round-3's 256x256 1-block/CU lockstep serializes ds_read vs MFMA
// segments; a co-resident anti-phased block overlaps them (and epilogue/tail:
// grid 5504 -> 10.75/11 rounds vs 5.375/6). Counted vmcnt preserved:
// A(t+1) staged @P0 (other parity), B(t+2) @P1 (same parity, after its reads
// drained), vmcnt(4) at tile end. Supertiled XCD swizzle for L2 locality.

#define M_TOTAL 8192
#define K_TOTAL 4096
#define N_TOTAL 11008
#define NT 32                       // K-tiles of BK=128 i8 bytes
#define NBM 64                      // 8192/128
#define NBN 86                      // 11008/128

typedef __attribute__((ext_vector_type(4))) int int4v;

__device__ inline ushort f2bf(float f) {
    union { __hip_bfloat16 h; ushort u; } cv;
    cv.h = __float2bfloat16(f);
    return cv.u;
}

// ---------------- x quantization: per-row absmax -> int8 (unchanged) ----------------

__global__ __launch_bounds__(256) void quant_x_kernel(const float* __restrict__ x,
                                                      signed char* __restrict__ xq,
                                                      float* __restrict__ sx) {
    const int row = blockIdx.x;
    const int tid = threadIdx.x;
    const float* xr = x + (size_t)row * K_TOTAL + tid * 16;

    float4 v0 = reinterpret_cast<const float4*>(xr)[0];
    float4 v1 = reinterpret_cast<const float4*>(xr)[1];
    float4 v2 = reinterpret_cast<const float4*>(xr)[2];
    float4 v3 = reinterpret_cast<const float4*>(xr)[3];

    float m = 0.f;
    m = fmaxf(m, fmaxf(fmaxf(fabsf(v0.x), fabsf(v0.y)), fmaxf(fabsf(v0.z), fabsf(v0.w))));
    m = fmaxf(m, fmaxf(fmaxf(fabsf(v1.x), fabsf(v1.y)), fmaxf(fabsf(v1.z), fabsf(v1.w))));
    m = fmaxf(m, fmaxf(fmaxf(fabsf(v2.x), fabsf(v2.y)), fmaxf(fabsf(v2.z), fabsf(v2.w))));
    m = fmaxf(m, fmaxf(fmaxf(fabsf(v3.x), fabsf(v3.y)), fmaxf(fabsf(v3.z), fabsf(v3.w))));

    for (int d = 1; d < 64; d <<= 1) m = fmaxf(m, __shfl_xor(m, d));
    __shared__ float wm_[4];
    if ((tid & 63) == 0) wm_[tid >> 6] = m;
    __syncthreads();
    m = fmaxf(fmaxf(wm_[0], wm_[1]), fmaxf(wm_[2], wm_[3]));

    const float inv = (m > 0.f) ? (127.f / m) : 0.f;
    if (tid == 0) sx[row] = (m > 0.f) ? (m / 127.f) : 0.f;

    float tmp[16] = {v0.x,v0.y,v0.z,v0.w, v1.x,v1.y,v1.z,v1.w,
                     v2.x,v2.y,v2.z,v2.w, v3.x,v3.y,v3.z,v3.w};
    int q[16];
#pragma unroll
    for (int i = 0; i < 16; ++i) {
        int t = __float2int_rn(tmp[i] * inv);
        q[i] = t > 127 ? 127 : (t < -127 ? -127 : t);
    }
    int4v o;
#pragma unroll
    for (int w = 0; w < 4; ++w)
        o[w] = (q[w*4] & 255) | ((q[w*4+1] & 255) << 8) |
               ((q[w*4+2] & 255) << 16) | ((q[w*4+3] & 255) << 24);
    *reinterpret_cast<int4v*>(xq + (size_t)row * K_TOTAL + tid * 16) = o;
}

// ---------------- W unpack: int32 wire (or packed int8) -> int8 (unchanged) ----------------

__global__ __launch_bounds__(256) void cvt_w_kernel(const int* __restrict__ in,
                                                    signed char* __restrict__ out, int nitems) {
    bool is8 = false;
    for (int i = 0; i < 256; ++i) {
        int v = in[i];
        if (v < -127 || v > 127) { is8 = true; break; }
    }
    int stride = gridDim.x * blockDim.x;
    if (!is8) {
        for (int i = blockIdx.x * blockDim.x + threadIdx.x; i < nitems; i += stride) {
            const int* p = in + (size_t)i * 16;
            int4v o;
#pragma unroll
            for (int w = 0; w < 4; ++w)
                o[w] = (p[w*4] & 255) | ((p[w*4+1] & 255) << 8) |
                       ((p[w*4+2] & 255) << 16) | ((p[w*4+3] & 255) << 24);
            *reinterpret_cast<int4v*>(out + (size_t)i * 16) = o;
        }
    } else {
        const int4v* in16 = reinterpret_cast<const int4v*>(in);
        for (int i = blockIdx.x * blockDim.x + threadIdx.x; i < nitems; i += stride)
            *reinterpret_cast<int4v*>(out + (size_t)i * 16) = in16[i];
    }
}

// ---------------- 128x128 i8 GEMM, 2 blocks/CU ----------------

#define GLOAD16(g, l) __builtin_amdgcn_global_load_lds( \
    (const __attribute__((address_space(1))) void*)(g), \
    (__attribute__((address_space(3))) void*)(l), 16, 0, 0)

// LDS (bytes): buf p*32768 + {A: [0,16K) | B: [16K,32K)}. Tile = 128 rows x 128 B.
// chunk = 8 rows = 1 KiB; 16 chunks/operand; wave wv stages chunks wv*4..wv*4+3.
// Swizzle: 16B granule g stored at g ^ (row&7); inverse applied on global src.

__global__ __launch_bounds__(256, 2) void gemm_kernel(const unsigned char* __restrict__ A,
                                                      const unsigned char* __restrict__ B,
                                                      const float* __restrict__ sx,
                                                      const float* __restrict__ scale,
                                                      const float* __restrict__ bias,
                                                      float* __restrict__ C) {
    __shared__ unsigned char sh[65536];  // 64 KiB -> 2 blocks/CU

    const int tid  = threadIdx.x;
    const int wv   = tid >> 6;      // 0..3
    const int lane = tid & 63;
    const int wm   = wv >> 1;       // 0..1
    const int wn   = wv & 1;        // 0..1

    // supertiled XCD swizzle: 5504 = 8 xcd * 688; per-xcd 8 bm x 86 bn in
    // 2 bands of 4 bm; 4x4 supertiles (tail 4x2) so co-resident blocks share panels.
    const int xcd = blockIdx.x & 7;
    const int l   = blockIdx.x >> 3;        // 0..687
    const int band = l / 344;
    const int lb   = l - band * 344;
    const int st   = lb >> 4;
    const int r    = lb & 15;
    int bm_l, bn;
    if (st < 21) { bm_l = band * 4 + (r >> 2); bn = st * 4 + (r & 3); }
    else         { bm_l = band * 4 + (r >> 1); bn = 84 + (r & 1); }
    const int bm = xcd * 8 + bm_l;

    // fragment-read geometry (byte offsets)
    const int fr  = lane & 15;
    const int fq  = lane >> 4;
    const int swz = fr & 7;
    const int kx0 = (fq ^ swz) * 16;         // K granules 0..3
    const int kx1 = ((4 + fq) ^ swz) * 16;   // K granules 4..7

    // staging source offsets (inverse-swizzled granule)
    const int c0 = wv * 4;
    const int rl = lane >> 3;
    const int sg = (lane & 7) ^ rl;
    size_t soff[4];
#pragma unroll
    for (int i = 0; i < 4; ++i)
        soff[i] = (size_t)((c0 + i) * 8 + rl) * K_TOTAL + sg * 16;

    const unsigned char* aS = A + (size_t)bm * 128 * K_TOTAL;
    const unsigned char* bS = B + (size_t)bn * 128 * K_TOTAL;

    int4v acc[4][4] = {};

    // ---- prologue: A(0)->buf0, B(0)->buf0, B(1)->buf1 (12 loads) ----
#pragma unroll
    for (int i = 0; i < 4; ++i) GLOAD16(aS + soff[i],       sh + (c0 + i) * 1024);
#pragma unroll
    for (int i = 0; i < 4; ++i) GLOAD16(bS + soff[i],       sh + 16384 + (c0 + i) * 1024);
#pragma unroll
    for (int i = 0; i < 4; ++i) GLOAD16(bS + 128 + soff[i], sh + 32768 + 16384 + (c0 + i) * 1024);
    asm volatile("s_waitcnt vmcnt(4)" ::: "memory");  // A(0),B(0) landed; B(1) in flight
    __builtin_amdgcn_s_barrier();

    // ---- main loop: 2 phases/tile; stage A(t+1)@P0 (other parity), B(t+2)@P1 (same parity) ----
#pragma unroll 1
    for (int t = 0; t < NT; ++t) {
        const int p = t & 1;
        const unsigned char* rd  = sh + (p << 15);
        unsigned char* stA = sh + ((p ^ 1) << 15);           // A(t+1)
        unsigned char* stB = sh + (p << 15) + 16384;         // B(t+2), same parity
        const unsigned char* aSrc = aS + (size_t)(t + 1) * 128;
        const unsigned char* bSrc = bS + (size_t)(t + 2) * 128;

        int4v af0[4], af1[4], bf0[4], bf1[4];

        // ---- P0: read af(K0) + bf(K0,K1); stage A(t+1); MFMA K0 ----
#pragma unroll
        for (int i = 0; i < 4; ++i) {
            const unsigned char* ap = rd + (wm * 64 + i * 16 + fr) * 128;
            af0[i] = *(const int4v*)(ap + kx0);
        }
#pragma unroll
        for (int n = 0; n < 4; ++n) {
            const unsigned char* bp = rd + 16384 + (wn * 64 + n * 16 + fr) * 128;
            bf0[n] = *(const int4v*)(bp + kx0);
            bf1[n] = *(const int4v*)(bp + kx1);
        }
        if (t + 1 < NT) {
#pragma unroll
            for (int i = 0; i < 4; ++i)
                GLOAD16(aSrc + soff[i], stA + (c0 + i) * 1024);
        }
        __builtin_amdgcn_s_barrier();
        asm volatile("s_waitcnt lgkmcnt(0)" ::: "memory");
        __builtin_amdgcn_s_setprio(1);
#pragma unroll
        for (int i = 0; i < 4; ++i)
#pragma unroll
            for (int n = 0; n < 4; ++n)
                acc[i][n] = __builtin_amdgcn_mfma_i32_16x16x64_i8(af0[i], bf0[n], acc[i][n], 0, 0, 0);
        __builtin_amdgcn_s_setprio(0);
        __builtin_amdgcn_s_barrier();

        // ---- P1: read af(K1); stage B(t+2); MFMA K1 ----
#pragma unroll
        for (int i = 0; i < 4; ++i) {
            const unsigned char* ap = rd + (wm * 64 + i * 16 + fr) * 128;
            af1[i] = *(const int4v*)(ap + kx1);
        }
        if (t + 2 < NT) {
#pragma unroll
            for (int i = 0; i < 4; ++i)
                GLOAD16(bSrc + soff[i], stB + (c0 + i) * 1024);
        }
        __builtin_amdgcn_s_barrier();
        asm volatile("s_waitcnt lgkmcnt(0)" ::: "memory");
        __builtin_amdgcn_s_setprio(1);
#pragma unroll
        for (int i = 0; i < 4; ++i)
#pragma unroll
            for (int n = 0; n < 4; ++n)
                acc[i][n] = __builtin_amdgcn_mfma_i32_16x16x64_i8(af1[i], bf1[n], acc[i][n], 0, 0, 0);
        __builtin_amdgcn_s_setprio(0);
        if (t + 2 < NT) { asm volatile("s_waitcnt vmcnt(4)" ::: "memory"); }
        else            { asm volatile("s_waitcnt vmcnt(0)" ::: "memory"); }
        __builtin_amdgcn_s_barrier();
    }

    // ---- epilogue: y = acc * sx[row]*scale[col] + bias[col] ----
    const int crow0 = bm * 128 + wm * 64;
    const int ccol0 = bn * 128 + wn * 64;
    float scv[4], bsv[4];
#pragma unroll
    for (int n = 0; n < 4; ++n) {
        const int col = ccol0 + n * 16 + fr;
        scv[n] = scale[col];
        bsv[n] = bias[col];
    }
#pragma unroll
    for (int fm = 0; fm < 4; ++fm) {
#pragma unroll
        for (int j = 0; j < 4; ++j) {
            const int row = crow0 + fm * 16 + fq * 4 + j;
            const float sr = sx[row];
            float* cp = C + (size_t)row * N_TOTAL + ccol0 + fr;
#pragma unroll
            for (int n = 0; n < 4; ++n)
                cp[n * 16] = (float)acc[fm][n][j] * (sr * scv[n]) + bsv[n];
        }
    }
}

// ---------------- fallback (ws too small): tiled f32 vector GEMM ----------------

__global__ __launch_bounds__(256) void gemm_fallback(const float* __restrict__ x,
                                                     const int* __restrict__ w,
                                                     const float* __restrict__ scale,
                                                     const float* __restrict__ bias,
                                                     float* __restrict__ C) {
    bool is8 = false;
    for (int i = 0; i < 256; ++i) {
        int v = w[i];
        if (v < -127 || v > 127) { is8 = true; break; }
    }
    const signed char* w8 = (const signed char*)w;

    __shared__ float As[64][16];
    __shared__ float Bs[64][16];
    const int nbn = N_TOTAL / 64;
    const int bm = blockIdx.x / nbn;
    const int bn = blockIdx.x % nbn;
    const int tid = threadIdx.x;
    const int tx = tid & 15, ty = tid >> 4;

    float acc[4][4] = {};
    for (int kt = 0; kt < K_TOTAL; kt += 16) {
        for (int i = 0; i < 4; ++i) {
            int idx = tid + i * 256;
            int r = idx >> 4, c = idx & 15;
            As[r][c] = x[(size_t)(bm * 64 + r) * K_TOTAL + kt + c];
            size_t widx = (size_t)(bn * 64 + r) * K_TOTAL + kt + c;
            Bs[r][c] = is8 ? (float)w8[widx] : (float)w[widx];
        }
        __syncthreads();
        for (int kk = 0; kk < 16; ++kk) {
            float a[4], b[4];
            for (int i = 0; i < 4; ++i) a[i] = As[ty * 4 + i][kk];
            for (int j = 0; j < 4; ++j) b[j] = Bs[tx * 4 + j][kk];
            for (int i = 0; i < 4; ++i)
                for (int j = 0; j < 4; ++j) acc[i][j] += a[i] * b[j];
        }
        __syncthreads();
    }
    for (int j = 0; j < 4; ++j) {
        int col = bn * 64 + tx * 4 + j;
        float s = scale[col], bb = bias[col];
        for (int i = 0; i < 4; ++i) {
            int row = bm * 64 + ty * 4 + i;
            C[(size_t)row * N_TOTAL + col] = acc[i][j] * s + bb;
        }
    }
}

// ---------------- launch ----------------

extern "C" void kernel_launch(void* const* d_in, const int* in_sizes, int n_in,
                              void* d_out, int out_size, void* d_ws, size_t ws_size,
                              hipStream_t stream) {
    const float* x     = (const float*)d_in[0];
    const int*   wq    = (const int*)d_in[1];
    const float* scale = (const float*)d_in[2];
    const float* bias  = (const float*)d_in[3];
    float*       out   = (float*)d_out;

    const size_t x_bytes = (size_t)M_TOTAL * K_TOTAL;
    const size_t w_bytes = (size_t)N_TOTAL * K_TOTAL;
    const size_t need = x_bytes + w_bytes + M_TOTAL * sizeof(float);

    if (ws_size >= need) {
        signed char* xq = (signed char*)d_ws;
        signed char* wb = (signed char*)d_ws + x_bytes;
        float*       sx = (float*)((char*)d_ws + x_bytes + w_bytes);

        quant_x_kernel<<<M_TOTAL, 256, 0, stream>>>(x, xq, sx);
        cvt_w_kernel<<<2048, 256, 0, stream>>>(wq, wb, (int)(w_bytes / 16));
        dim3 grid(NBM * NBN);  // 64*86 = 5504
        gemm_kernel<<<grid, 256, 0, stream>>>((const unsigned char*)xq,
                                              (const unsigned char*)wb,
                                              sx, scale, bias, out);
    } else {
        dim3 grid((M_TOTAL / 64) * (N_TOTAL / 64));
        gemm_fallback<<<grid, 256, 0, stream>>>(x, wq, scale, bias, out);
    }
}